// Round 8
// baseline (127.794 us; speedup 1.0000x reference)
//
#include <hip/hip_runtime.h>

#define BN 4096
#define KD 256
#define TILE 128
#define BK 64

typedef short bf16x8 __attribute__((ext_vector_type(8)));
typedef float f32x4 __attribute__((ext_vector_type(4)));
typedef unsigned short ushort_t;
typedef unsigned int uint_t;

// tile slots: z=0 upper-tri 528, z=1 upper-tri 528, z=2 full 1024 -> 2080
#define NSLOT 2080
#define RECW 20   // floats per slot record: h~, dsum, A[5], B[5], C[5] (+pad)

__device__ inline void async_load16(const void* g, void* l) {
    __builtin_amdgcn_global_load_lds((const __attribute__((address_space(1))) void*)g,
                                     (__attribute__((address_space(3))) void*)l,
                                     16, 0, 0);
}

__device__ inline ushort_t f2bf(float f) {
    union { float f; unsigned int u; } x;
    x.f = f;
    unsigned int u = x.u;
    unsigned int r = (u + 0x7fffu + ((u >> 16) & 1u)) >> 16;  // RTNE
    return (ushort_t)r;
}

__device__ __forceinline__ float fast_sqrt(float x) {
    return __builtin_amdgcn_sqrtf(x);     // v_sqrt_f32
}
__device__ __forceinline__ float fast_exp2(float x) {
    return __builtin_amdgcn_exp2f(x);     // v_exp_f32
}

__device__ __forceinline__ void decode_slot(int slot, int& z, int& bi, int& bj) {
    if (slot >= 1056) {
        z = 2; int t = slot - 1056; bi = t >> 5; bj = t & 31;
    } else {
        z = (slot >= 528) ? 1 : 0;
        int t = slot - z * 528;
        int b = (int)(32.5f - sqrtf(1056.25f - 2.0f * (float)t));
        while (b * (65 - b) / 2 > t) --b;
        while ((b + 1) * (64 - b) / 2 <= t) ++b;
        bi = b;
        bj = bi + (t - bi * (65 - bi) / 2);
    }
}

// Kernel 0: fp32 row norms + bf16 (RTNE) copies of xs, xt.
__global__ __launch_bounds__(256) void norm_cvt(
        const float* __restrict__ xs, const float* __restrict__ xt,
        ushort_t* __restrict__ xsb, ushort_t* __restrict__ xtb,
        float* __restrict__ norms) {
    int w = threadIdx.x >> 6;
    int lane = threadIdx.x & 63;
    int row = blockIdx.x * 4 + w;              // 0..8191
    const float* src = (row < BN) ? xs + (size_t)row * KD
                                  : xt + (size_t)(row - BN) * KD;
    ushort_t* dst = (row < BN) ? xsb + (size_t)row * KD
                               : xtb + (size_t)(row - BN) * KD;
    float4 v = ((const float4*)src)[lane];
    float s = v.x * v.x + v.y * v.y + v.z * v.z + v.w * v.w;
#pragma unroll
    for (int off = 32; off > 0; off >>= 1) s += __shfl_xor(s, off, 64);
    if (lane == 0) norms[row] = s;
    ushort4 o;
    o.x = f2bf(v.x); o.y = f2bf(v.y); o.z = f2bf(v.z); o.w = f2bf(v.w);
    ((ushort4*)dst)[lane] = o;
}

// -------- single GEMM pass: d, per-tile d-sum, and Taylor-centered exp-sums --------
// Per block: compute 128x128 d-tile (exact fp32); local mean m~ -> center
// h~ = log2e/(4 m~) (alpha=2); accumulate A_k=sum u^(2^k), B_k=sum d u^(2^k),
// C_k=sum d^2 u^(2^k), u=2^(-d h~), k=0..4 covering alphas {2,1,1/2,1/4,1/8}.
// Finalize corrects each slot to the exact global per-z mean via 2nd-order Taylor:
// S(h) = A - ln2*delta*B + 0.5*ln2^2*delta^2*C, delta_k = 2^k (h_z - h~).
// Residual is cubic (~1e-9 rel) since |h_z - h~|/h ~ 3.5e-4 for 16K-entry tiles.

__global__ __launch_bounds__(256) void mmd_main(
        const ushort_t* __restrict__ xsb, const ushort_t* __restrict__ xtb,
        const float* __restrict__ norms, float* __restrict__ rec) {
    const int slot = blockIdx.x;
    int z, bi, bj;
    decode_slot(slot, z, bi, bj);

    const ushort_t* X = (z == 1) ? xtb : xsb;
    const ushort_t* Y = (z == 0) ? xsb : xtb;
    const float* nX = norms + ((z == 1) ? BN : 0);
    const float* nY = norms + ((z == 0) ? 0 : BN);

    const int tid = threadIdx.x;
    const int lane = tid & 63;
    const int w = tid >> 6;
    const int wr = w >> 1;
    const int wc = w & 1;
    const int m16 = lane & 15;
    const int q = lane >> 4;

    const int i0 = bi * TILE;
    const int j0 = bj * TILE;

    __shared__ ushort_t lA[TILE * BK];
    __shared__ ushort_t lB[TILE * BK];
    __shared__ float redw[4];
    __shared__ float fin[15][4];

    f32x4 acc[4][4] = {};

#pragma unroll
    for (int kk = 0; kk < KD; kk += BK) {
        __syncthreads();
#pragma unroll
        for (int t = 0; t < 4; ++t) {
            int rowblk = w * 4 + t;
            int r = rowblk * 8 + (lane >> 3);
            int cch = lane & 7;
            int gch = cch ^ (r & 7);
            const ushort_t* gA = X + (size_t)(i0 + r) * KD + (kk + gch * 8);
            const ushort_t* gB = Y + (size_t)(j0 + r) * KD + (kk + gch * 8);
            async_load16(gA, (char*)lA + rowblk * 1024);
            async_load16(gB, (char*)lB + rowblk * 1024);
        }
        __syncthreads();

#pragma unroll
        for (int ks = 0; ks < 2; ++ks) {
            bf16x8 af[4], bfr[4];
            int kap = ks * 4 + q;
#pragma unroll
            for (int rg = 0; rg < 4; ++rg) {
                int rowa = wr * 64 + rg * 16 + m16;
                int posa = kap ^ (rowa & 7);
                af[rg] = *(const bf16x8*)&lA[rowa * BK + posa * 8];
                int rowb = wc * 64 + rg * 16 + m16;
                int posb = kap ^ (rowb & 7);
                bfr[rg] = *(const bf16x8*)&lB[rowb * BK + posb * 8];
            }
#pragma unroll
            for (int rg = 0; rg < 4; ++rg)
#pragma unroll
                for (int ng = 0; ng < 4; ++ng)
                    acc[rg][ng] = __builtin_amdgcn_mfma_f32_16x16x32_bf16(
                        af[rg], bfr[ng], acc[rg][ng], 0, 0, 0);
        }
    }

    float nxv[16];
#pragma unroll
    for (int rg = 0; rg < 4; ++rg)
#pragma unroll
        for (int rr = 0; rr < 4; ++rr)
            nxv[rg * 4 + rr] = nX[i0 + wr * 64 + rg * 16 + q * 4 + rr];
    float nyv[4];
#pragma unroll
    for (int ng = 0; ng < 4; ++ng)
        nyv[ng] = nY[j0 + wc * 64 + ng * 16 + m16];

    // ---- phase A: d per entry (in-place over acc), raw block sum ----
    const bool diag = (z < 2 && bi == bj);
    float dsum = 0.0f;
#pragma unroll
    for (int rg = 0; rg < 4; ++rg) {
#pragma unroll
        for (int ng = 0; ng < 4; ++ng) {
#pragma unroll
            for (int rr = 0; rr < 4; ++rr) {
                float sq = nxv[rg * 4 + rr] + nyv[ng] - 2.0f * acc[rg][ng][rr];
                sq = fmaxf(sq, 0.0f);
                float d = fast_sqrt(sq);
                if (diag) {
                    int i = wr * 64 + rg * 16 + q * 4 + rr;
                    int j = wc * 64 + ng * 16 + m16;
                    if (i == j) d = 0.0f;              // exact-zero diagonal
                }
                acc[rg][ng][rr] = d;                   // keep d for phase B
                dsum += d;
            }
        }
    }
#pragma unroll
    for (int off = 32; off > 0; off >>= 1) dsum += __shfl_xor(dsum, off, 64);
    if (lane == 0) redw[w] = dsum;
    __syncthreads();
    const float bsum = redw[0] + redw[1] + redw[2] + redw[3];
    const float mloc = bsum * (1.0f / 16384.0f);       // tile-local mean of d
    const float ht = 1.4426950408889634f / (4.0f * fmaxf(mloc, 1e-20f)); // alpha=2 center
    const float nh = -ht;

    // ---- phase B: centered exp-sums (one exp2 per entry, power chaining) ----
    float Av[5] = {}, Bv[5] = {}, Cv[5] = {};
#pragma unroll
    for (int rg = 0; rg < 4; ++rg) {
#pragma unroll
        for (int ng = 0; ng < 4; ++ng) {
#pragma unroll
            for (int rr = 0; rr < 4; ++rr) {
                float d = acc[rg][ng][rr];
                float u = fast_exp2(d * nh);           // u = 2^(-d*h~)
                float p = u;
                float dp = d * u;
#pragma unroll
                for (int k = 0; k < 5; ++k) {
                    Av[k] += p;
                    Bv[k] += dp;
                    Cv[k] += d * dp;
                    if (k < 4) { float po = p; p = po * po; dp = dp * po; }
                }
            }
        }
    }
#pragma unroll
    for (int k = 0; k < 5; ++k) {
#pragma unroll
        for (int off = 32; off > 0; off >>= 1) {
            Av[k] += __shfl_xor(Av[k], off, 64);
            Bv[k] += __shfl_xor(Bv[k], off, 64);
            Cv[k] += __shfl_xor(Cv[k], off, 64);
        }
    }
    if (lane == 0) {
#pragma unroll
        for (int k = 0; k < 5; ++k) {
            fin[k][w] = Av[k];
            fin[5 + k][w] = Bv[k];
            fin[10 + k][w] = Cv[k];
        }
    }
    __syncthreads();
    if (tid == 0) {
        float c1 = (z < 2 && bi != bj) ? 2.0f : 1.0f;  // symmetric-tile weight
        float* r = rec + (size_t)slot * RECW;
        r[0] = ht;
        r[1] = c1 * bsum;
#pragma unroll
        for (int k = 0; k < 15; ++k)
            r[2 + k] = c1 * (fin[k][0] + fin[k][1] + fin[k][2] + fin[k][3]);
    }
}

// -------- finalize: per-z means, Taylor-correct slot sums, loss (1 block) --------

__global__ __launch_bounds__(256) void mmd_fin(
        const float* __restrict__ rec, float* __restrict__ out) {
    const int tid = threadIdx.x;
    const int lane = tid & 63, w = tid >> 6;
    __shared__ double rz[4][3];
    __shared__ double hsh[3];

    // phase 1: exact per-z distance sums -> h_z
    double a0 = 0.0, a1 = 0.0, a2 = 0.0;
    for (int s = tid; s < NSLOT; s += 256) {
        double v = (double)rec[(size_t)s * RECW + 1];
        if (s < 528) a0 += v; else if (s < 1056) a1 += v; else a2 += v;
    }
#pragma unroll
    for (int off = 32; off > 0; off >>= 1) {
        a0 += __shfl_xor(a0, off, 64);
        a1 += __shfl_xor(a1, off, 64);
        a2 += __shfl_xor(a2, off, 64);
    }
    if (lane == 0) { rz[w][0] = a0; rz[w][1] = a1; rz[w][2] = a2; }
    __syncthreads();
    if (tid == 0) {
#pragma unroll
        for (int zz = 0; zz < 3; ++zz) {
            double sz = rz[0][zz] + rz[1][zz] + rz[2][zz] + rz[3][zz];
            double mz = sz * (1.0 / 16777216.0);       // mean over 4096^2
            hsh[zz] = 1.4426950408889634 / (4.0 * mz); // alpha=2 exponent scale
        }
    }
    __syncthreads();
    const float h0 = (float)hsh[0], h1 = (float)hsh[1], h2 = (float)hsh[2];

    // phase 2: Taylor-corrected per-slot sums
    double tot = 0.0;
    for (int s = tid; s < NSLOT; s += 256) {
        const float* r = rec + (size_t)s * RECW;
        int zz = (s < 528) ? 0 : ((s < 1056) ? 1 : 2);
        float hz = (zz == 0) ? h0 : ((zz == 1) ? h1 : h2);
        float e0 = 0.6931471805599453f * (hz - r[0]);  // ln2 * delta_0
        float sub = 0.0f;
#pragma unroll
        for (int k = 0; k < 5; ++k) {
            float ek = e0 * (float)(1 << k);
            sub += r[2 + k] - ek * r[7 + k] + 0.5f * ek * ek * r[12 + k];
        }
        double coef = (zz == 2) ? -2.0 : 1.0;          // kxx + kyy - 2 kxy
        tot += coef * (double)sub;
    }
#pragma unroll
    for (int off = 32; off > 0; off >>= 1) tot += __shfl_xor(tot, off, 64);
    if (lane == 0) rz[w][0] = tot;
    __syncthreads();
    if (tid == 0) {
        double S = rz[0][0] + rz[1][0] + rz[2][0] + rz[3][0];
        double l = sqrt(S / ((double)BN * (double)(BN - 1)));
        float f = (float)l;
        if (!(f == f)) f = 0.0f;
        out[0] = f;
    }
}

extern "C" void kernel_launch(void* const* d_in, const int* in_sizes, int n_in,
                              void* d_out, int out_size, void* d_ws, size_t ws_size,
                              hipStream_t stream) {
    const float* xs = (const float*)d_in[0];
    const float* xt = (const float*)d_in[1];
    float* out = (float*)d_out;

    char* ws = (char*)d_ws;
    float* rec = (float*)ws;                       // 2080*20 floats = 166400 -> pad 166464
    float* norms = (float*)(ws + 166464);          // 8192 floats -> ends 199232 (pad 199296)
    ushort_t* xsb = (ushort_t*)(ws + 199296);      // 2 MB
    ushort_t* xtb = xsb + (size_t)BN * KD;         // 2 MB -> ends 4393600

    size_t need = 4393600;
    if (ws_size < need) {
        (void)hipMemsetAsync(d_out, 0xC0, 4, stream);    // diagnostic marker
        return;
    }

    norm_cvt<<<2048, 256, 0, stream>>>(xs, xt, xsb, xtb, norms);
    mmd_main<<<NSLOT, 256, 0, stream>>>(xsb, xtb, norms, rec);
    mmd_fin<<<1, 256, 0, stream>>>(rec, out);
}